// Round 3
// baseline (16483.502 us; speedup 1.0000x reference)
//
#include <hip/hip_runtime.h>

#define T_STEPS 256
#define BATCH   256
#define DIN     1024
#define DH      1024

typedef _Float16 half8_t __attribute__((ext_vector_type(8)));
typedef _Float16 half4_t __attribute__((ext_vector_type(4)));
typedef float    f32x4_t __attribute__((ext_vector_type(4)));

#define LDH 1032   // padded LDS row stride (halves): 2064 B, spreads banks

// Fast tanh: tanh(x) = 1 - 2/(exp2(2*log2e*x)+1). v_exp + v_rcp, saturates
// correctly at +/-1 for large |x|; error ~1e-7 << fp16 h quantization.
__device__ __forceinline__ float ftanh(float x) {
    float t = x * 2.885390081777927f;   // 2*log2(e)
#if __has_builtin(__builtin_amdgcn_exp2f)
    float e = __builtin_amdgcn_exp2f(t);
#else
    float e = exp2f(t);
#endif
    float r = __builtin_amdgcn_rcpf(e + 1.0f);
    return 1.0f - 2.0f * r;
}

// ---------------------------------------------------------------------------
// Split W (1024 x 2048 fp32) into Wh = W[:, :1024] and Wx = W[:, 1024:], fp16.
// ---------------------------------------------------------------------------
__global__ __launch_bounds__(256) void cvt_w(const float* __restrict__ W,
                                             _Float16* __restrict__ Wh,
                                             _Float16* __restrict__ Wx) {
    const int part = blockIdx.x >> 9;                         // 0: Wh, 1: Wx
    size_t base = ((size_t)(blockIdx.x & 511) * 256 + threadIdx.x) * 8;
    const int n = (int)(base >> 10);
    const int k = (int)(base & 1023);
    const float4* s = reinterpret_cast<const float4*>(W + (size_t)n * 2048 + part * 1024 + k);
    float4 a = s[0], b = s[1];
    half8_t h;
    h[0] = (_Float16)a.x; h[1] = (_Float16)a.y;
    h[2] = (_Float16)a.z; h[3] = (_Float16)a.w;
    h[4] = (_Float16)b.x; h[5] = (_Float16)b.y;
    h[6] = (_Float16)b.z; h[7] = (_Float16)b.w;
    _Float16* dst = part ? Wx : Wh;
    *reinterpret_cast<half8_t*>(dst + base) = h;
}

// ---------------------------------------------------------------------------
// out[0] = h0 = zeros.
// ---------------------------------------------------------------------------
__global__ __launch_bounds__(256) void zero_h0(float* __restrict__ out) {
    size_t i = (size_t)blockIdx.x * 256 + threadIdx.x;
    reinterpret_cast<float4*>(out)[i] = make_float4(0.f, 0.f, 0.f, 0.f);
}

// ---------------------------------------------------------------------------
// Z = seq @ Wx^T + bias, written into out[1..256]. (unchanged)
// ---------------------------------------------------------------------------
__global__ __launch_bounds__(256) void zgemm(const float* __restrict__ seq,
                                             const _Float16* __restrict__ Wx,
                                             const float* __restrict__ bias,
                                             float* __restrict__ out) {
    __shared__ _Float16 la[64 * 136];
    __shared__ _Float16 lb[64 * 136];

    const int tid  = threadIdx.x;
    const int nblk = blockIdx.x;   // 0..15
    const int mblk = blockIdx.y;   // 0..1023

    const float* __restrict__ X = seq + (size_t)mblk * 64 * 1024;
    float* __restrict__ Z = out + (size_t)BATCH * DH + (size_t)mblk * 64 * 1024;

    const int ar = tid >> 2;
    const int ac = (tid & 3) * 32;
    const int br = tid >> 2;
    const int bc = (tid & 3) * 32;
    const _Float16* Bsrc = Wx + (size_t)(nblk * 64 + br) * 1024;

    float4 af[8];
    uint4  bp[4];

    auto load_tiles = [&](int kb) {
        const float4* s4 = reinterpret_cast<const float4*>(X + (size_t)ar * 1024 + kb + ac);
#pragma unroll
        for (int i = 0; i < 8; ++i) af[i] = s4[i];
        const uint4* sb = reinterpret_cast<const uint4*>(Bsrc + kb + bc);
#pragma unroll
        for (int i = 0; i < 4; ++i) bp[i] = sb[i];
    };
    auto store_tiles = [&]() {
#pragma unroll
        for (int i = 0; i < 4; ++i) {
            half8_t h;
            h[0] = (_Float16)af[2 * i].x; h[1] = (_Float16)af[2 * i].y;
            h[2] = (_Float16)af[2 * i].z; h[3] = (_Float16)af[2 * i].w;
            h[4] = (_Float16)af[2 * i + 1].x; h[5] = (_Float16)af[2 * i + 1].y;
            h[6] = (_Float16)af[2 * i + 1].z; h[7] = (_Float16)af[2 * i + 1].w;
            *reinterpret_cast<half8_t*>(&la[ar * 136 + ac + 8 * i]) = h;
        }
        uint4* d = reinterpret_cast<uint4*>(&lb[br * 136 + bc]);
#pragma unroll
        for (int i = 0; i < 4; ++i) d[i] = bp[i];
    };

    const int wave = tid >> 6;
    const int lane = tid & 63;
    const int fr   = lane & 15;
    const int quad = lane >> 4;
    const int wm   = (wave >> 1) * 32;
    const int wn   = (wave & 1) * 32;

    f32x4_t acc[2][2] = {{{0.f,0.f,0.f,0.f},{0.f,0.f,0.f,0.f}},
                         {{0.f,0.f,0.f,0.f},{0.f,0.f,0.f,0.f}}};

    load_tiles(0);
#pragma unroll 1
    for (int it = 0; it < 8; ++it) {
        store_tiles();
        __syncthreads();
        if (it < 7) load_tiles((it + 1) * 128);
        const _Float16* pa0 = &la[(wm + fr) * 136 + quad * 8];
        const _Float16* pa1 = &la[(wm + 16 + fr) * 136 + quad * 8];
        const _Float16* pb0 = &lb[(wn + fr) * 136 + quad * 8];
        const _Float16* pb1 = &lb[(wn + 16 + fr) * 136 + quad * 8];
#pragma unroll
        for (int kk = 0; kk < 4; ++kk) {
            half8_t a0 = *reinterpret_cast<const half8_t*>(pa0 + kk * 32);
            half8_t a1 = *reinterpret_cast<const half8_t*>(pa1 + kk * 32);
            half8_t b0 = *reinterpret_cast<const half8_t*>(pb0 + kk * 32);
            half8_t b1 = *reinterpret_cast<const half8_t*>(pb1 + kk * 32);
            acc[0][0] = __builtin_amdgcn_mfma_f32_16x16x32_f16(a0, b0, acc[0][0], 0, 0, 0);
            acc[0][1] = __builtin_amdgcn_mfma_f32_16x16x32_f16(a0, b1, acc[0][1], 0, 0, 0);
            acc[1][0] = __builtin_amdgcn_mfma_f32_16x16x32_f16(a1, b0, acc[1][0], 0, 0, 0);
            acc[1][1] = __builtin_amdgcn_mfma_f32_16x16x32_f16(a1, b1, acc[1][1], 0, 0, 0);
        }
        __syncthreads();
    }

    const float bv0 = bias[nblk * 64 + wn + fr];
    const float bv1 = bias[nblk * 64 + wn + 16 + fr];
#pragma unroll
    for (int i = 0; i < 2; ++i) {
        const int ml = wm + i * 16 + quad * 4;
#pragma unroll
        for (int r = 0; r < 4; ++r) {
            Z[(size_t)(ml + r) * 1024 + nblk * 64 + wn + fr]      = acc[i][0][r] + bv0;
            Z[(size_t)(ml + r) * 1024 + nblk * 64 + wn + 16 + fr] = acc[i][1][r] + bv1;
        }
    }
}

// ---------------------------------------------------------------------------
// Communication-free recurrence. 16 WGs x 512 threads; WG b owns batch rows
// [b*16, b*16+16) for ALL 1024 hidden columns -> h lives in this WG's LDS
// (ping-pong fp16 buffers), zero inter-WG traffic, one barrier per step.
// Wave w (0..7) owns the 128-col strip [w*128, w*128+128).
// MFMA orientation computes out^T: A = Wh rows (streamed from L2, 16B/lane
// contiguous), B = h from LDS, D: col(lane&15)=batch row, row(quad*4+r)=
// 4 consecutive hidden cols -> float4 global store + half4 LDS store.
// Per wave per step: 8 nf x 32 ks = 256 MFMAs; Wh re-streamed from L2
// (2 MB/WG/step, L2-resident: 2 WGs/XCD < 4 MB L2).
// ---------------------------------------------------------------------------
__global__ __launch_bounds__(512, 1) void rnn_seq(const _Float16* __restrict__ Wh,
                                                  float* __restrict__ out) {
    __shared__ __align__(16) _Float16 hA[16 * LDH];
    __shared__ __align__(16) _Float16 hB[16 * LDH];

    const int tid  = threadIdx.x;
    const int wave = tid >> 6;          // 0..7
    const int lane = tid & 63;
    const int fr   = lane & 15;         // batch row within tile / Wh-row offset
    const int quad = lane >> 4;         // 0..3
    const int r0   = blockIdx.x * 16;   // global batch rows r0..r0+15
    const int c0   = wave * 128;        // this wave's hidden-col strip

    // Per-lane base for Wh loads: row = c0 + nf*16 + fr, k = ks*32 + quad*8.
    const _Float16* aBase = Wh + (size_t)(c0 + fr) * DH + quad * 8;

    // ---- prologue: h1 = tanh(Z1) since h0 == 0; write out[1] and hA ----
    {
        float* o = out + ((size_t)BATCH + (size_t)(r0 + fr)) * DH + c0 + quad * 4;
#pragma unroll
        for (int nf = 0; nf < 8; ++nf) {
            float4 z = *reinterpret_cast<const float4*>(o + nf * 16);
            float4 v = make_float4(ftanh(z.x), ftanh(z.y), ftanh(z.z), ftanh(z.w));
            *reinterpret_cast<float4*>(o + nf * 16) = v;
            half4_t h4;
            h4[0] = (_Float16)v.x; h4[1] = (_Float16)v.y;
            h4[2] = (_Float16)v.z; h4[3] = (_Float16)v.w;
            *reinterpret_cast<half4_t*>(&hA[fr * LDH + c0 + nf * 16 + quad * 4]) = h4;
        }
    }
    __syncthreads();

    // ---- steps s = 1..255: h_{s+1} = tanh(h_s @ Wh^T + Z_{s+1}) ----
#pragma unroll 1
    for (int s = 1; s < T_STEPS; ++s) {
        const _Float16* hc = (s & 1) ? hA : hB;   // s=1 reads hA
        _Float16*       hn = (s & 1) ? hB : hA;

        float* o = out + ((size_t)(s + 1) * BATCH + (size_t)(r0 + fr)) * DH
                       + c0 + quad * 4;

        // Z prefetch (own elements; same lane reads then overwrites).
        float4 z[8];
#pragma unroll
        for (int nf = 0; nf < 8; ++nf)
            z[nf] = *reinterpret_cast<const float4*>(o + nf * 16);

        f32x4_t acc[8];
#pragma unroll
        for (int nf = 0; nf < 8; ++nf) acc[nf] = (f32x4_t){0.f, 0.f, 0.f, 0.f};

        const _Float16* bl = hc + fr * LDH + quad * 8;
#pragma unroll 2
        for (int ks = 0; ks < 32; ++ks) {
            half8_t b = *reinterpret_cast<const half8_t*>(bl + ks * 32);
#pragma unroll
            for (int nf = 0; nf < 8; ++nf) {
                half8_t a = *reinterpret_cast<const half8_t*>(
                    aBase + (size_t)nf * 16 * DH + ks * 32);
                acc[nf] = __builtin_amdgcn_mfma_f32_16x16x32_f16(a, b, acc[nf], 0, 0, 0);
            }
        }

        // Epilogue: v = tanh(acc + Z); out fp32 (float4) + next-h fp16 (half4).
#pragma unroll
        for (int nf = 0; nf < 8; ++nf) {
            float4 v = make_float4(ftanh(acc[nf][0] + z[nf].x),
                                   ftanh(acc[nf][1] + z[nf].y),
                                   ftanh(acc[nf][2] + z[nf].z),
                                   ftanh(acc[nf][3] + z[nf].w));
            *reinterpret_cast<float4*>(o + nf * 16) = v;
            half4_t h4;
            h4[0] = (_Float16)v.x; h4[1] = (_Float16)v.y;
            h4[2] = (_Float16)v.z; h4[3] = (_Float16)v.w;
            *reinterpret_cast<half4_t*>(&hn[fr * LDH + c0 + nf * 16 + quad * 4]) = h4;
        }
        __syncthreads();   // hn complete before next step reads it
    }
}

// ---------------------------------------------------------------------------
// Workspace layout (bytes): [0, 2M) Wh fp16; [2M, 4M) Wx fp16.
// ---------------------------------------------------------------------------
extern "C" void kernel_launch(void* const* d_in, const int* in_sizes, int n_in,
                              void* d_out, int out_size, void* d_ws, size_t ws_size,
                              hipStream_t stream) {
    const float* seq  = (const float*)d_in[0];   // (256, 256, 1024) fp32
    const float* W    = (const float*)d_in[1];   // (1024, 2048) fp32
    const float* bias = (const float*)d_in[2];   // (1024,) fp32
    float* out        = (float*)d_out;           // (257, 256, 1024) fp32
    _Float16* Wh      = (_Float16*)d_ws;
    _Float16* Wx      = (_Float16*)d_ws + 1024 * 1024;

    hipLaunchKernelGGL(cvt_w, dim3(1024), dim3(256), 0, stream, W, Wh, Wx);
    hipLaunchKernelGGL(zero_h0, dim3(256), dim3(256), 0, stream, out);
    hipLaunchKernelGGL(zgemm, dim3(16, 1024), dim3(256), 0, stream, seq, Wx, bias, out);
    hipLaunchKernelGGL(rnn_seq, dim3(16), dim3(512), 0, stream, Wh, out);
}

// Round 4
// 2042.075 us; speedup vs baseline: 8.0719x; 8.0719x over previous
//
#include <hip/hip_runtime.h>

#define T_STEPS 256
#define BATCH   256
#define DIN     1024
#define DH      1024

typedef _Float16 half8_t __attribute__((ext_vector_type(8)));
typedef _Float16 half4_t __attribute__((ext_vector_type(4)));
typedef float    f32x4_t __attribute__((ext_vector_type(4)));

#define LDH  1032   // padded LDS row stride (halves) for h slab
#define REDW 68     // padded row stride (floats) for epilogue transpose

// aux/cpol bits on gfx950: bit0 = sc0, bit4 = sc1 -> 17 = system-scope bypass
#define CPOL_SYS 17

union H4U { half4_t h; unsigned long long u; };

// Fast tanh: 1 - 2/(exp2(2*log2e*x)+1); error ~1e-7 << fp16 h quantization.
__device__ __forceinline__ float ftanh(float x) {
    float t = x * 2.885390081777927f;   // 2*log2(e)
    float e = exp2f(t);
    float r = __builtin_amdgcn_rcpf(e + 1.0f);
    return 1.0f - 2.0f * r;
}

// ---------------------------------------------------------------------------
// Split W (1024 x 2048 fp32) into Wh = W[:, :1024] and Wx = W[:, 1024:], fp16.
// ---------------------------------------------------------------------------
__global__ __launch_bounds__(256) void cvt_w(const float* __restrict__ W,
                                             _Float16* __restrict__ Wh,
                                             _Float16* __restrict__ Wx) {
    const int part = blockIdx.x >> 9;                         // 0: Wh, 1: Wx
    size_t base = ((size_t)(blockIdx.x & 511) * 256 + threadIdx.x) * 8;
    const int n = (int)(base >> 10);
    const int k = (int)(base & 1023);
    const float4* s = reinterpret_cast<const float4*>(W + (size_t)n * 2048 + part * 1024 + k);
    float4 a = s[0], b = s[1];
    half8_t h;
    h[0] = (_Float16)a.x; h[1] = (_Float16)a.y;
    h[2] = (_Float16)a.z; h[3] = (_Float16)a.w;
    h[4] = (_Float16)b.x; h[5] = (_Float16)b.y;
    h[6] = (_Float16)b.z; h[7] = (_Float16)b.w;
    _Float16* dst = part ? Wx : Wh;
    *reinterpret_cast<half8_t*>(dst + base) = h;
}

// ---------------------------------------------------------------------------
// out[0] = zeros; block 0 zeroes the 256 sync flags (16-int stride) with
// system-scope (write-through) stores so no stale L2 copy can exist.
// ---------------------------------------------------------------------------
__global__ __launch_bounds__(256) void zero_h0(float* __restrict__ out,
                                               int* __restrict__ flags) {
    size_t i = (size_t)blockIdx.x * 256 + threadIdx.x;
    reinterpret_cast<float4*>(out)[i] = make_float4(0.f, 0.f, 0.f, 0.f);
    if (blockIdx.x == 0) {
#pragma unroll
        for (int j = 0; j < 16; ++j)
            __hip_atomic_store(&flags[(int)threadIdx.x * 16 + j], 0,
                               __ATOMIC_RELAXED, __HIP_MEMORY_SCOPE_SYSTEM);
    }
}

// ---------------------------------------------------------------------------
// Z = seq @ Wx^T + bias, written into out[1..256]. (unchanged)
// ---------------------------------------------------------------------------
__global__ __launch_bounds__(256) void zgemm(const float* __restrict__ seq,
                                             const _Float16* __restrict__ Wx,
                                             const float* __restrict__ bias,
                                             float* __restrict__ out) {
    __shared__ _Float16 la[64 * 136];
    __shared__ _Float16 lb[64 * 136];

    const int tid  = threadIdx.x;
    const int nblk = blockIdx.x;   // 0..15
    const int mblk = blockIdx.y;   // 0..1023

    const float* __restrict__ X = seq + (size_t)mblk * 64 * 1024;
    float* __restrict__ Z = out + (size_t)BATCH * DH + (size_t)mblk * 64 * 1024;

    const int ar = tid >> 2;
    const int ac = (tid & 3) * 32;
    const int br = tid >> 2;
    const int bc = (tid & 3) * 32;
    const _Float16* Bsrc = Wx + (size_t)(nblk * 64 + br) * 1024;

    float4 af[8];
    uint4  bp[4];

    auto load_tiles = [&](int kb) {
        const float4* s4 = reinterpret_cast<const float4*>(X + (size_t)ar * 1024 + kb + ac);
#pragma unroll
        for (int i = 0; i < 8; ++i) af[i] = s4[i];
        const uint4* sb = reinterpret_cast<const uint4*>(Bsrc + kb + bc);
#pragma unroll
        for (int i = 0; i < 4; ++i) bp[i] = sb[i];
    };
    auto store_tiles = [&]() {
#pragma unroll
        for (int i = 0; i < 4; ++i) {
            half8_t h;
            h[0] = (_Float16)af[2 * i].x; h[1] = (_Float16)af[2 * i].y;
            h[2] = (_Float16)af[2 * i].z; h[3] = (_Float16)af[2 * i].w;
            h[4] = (_Float16)af[2 * i + 1].x; h[5] = (_Float16)af[2 * i + 1].y;
            h[6] = (_Float16)af[2 * i + 1].z; h[7] = (_Float16)af[2 * i + 1].w;
            *reinterpret_cast<half8_t*>(&la[ar * 136 + ac + 8 * i]) = h;
        }
        uint4* d = reinterpret_cast<uint4*>(&lb[br * 136 + bc]);
#pragma unroll
        for (int i = 0; i < 4; ++i) d[i] = bp[i];
    };

    const int wave = tid >> 6;
    const int lane = tid & 63;
    const int fr   = lane & 15;
    const int quad = lane >> 4;
    const int wm   = (wave >> 1) * 32;
    const int wn   = (wave & 1) * 32;

    f32x4_t acc[2][2] = {{{0.f,0.f,0.f,0.f},{0.f,0.f,0.f,0.f}},
                         {{0.f,0.f,0.f,0.f},{0.f,0.f,0.f,0.f}}};

    load_tiles(0);
#pragma unroll 1
    for (int it = 0; it < 8; ++it) {
        store_tiles();
        __syncthreads();
        if (it < 7) load_tiles((it + 1) * 128);
        const _Float16* pa0 = &la[(wm + fr) * 136 + quad * 8];
        const _Float16* pa1 = &la[(wm + 16 + fr) * 136 + quad * 8];
        const _Float16* pb0 = &lb[(wn + fr) * 136 + quad * 8];
        const _Float16* pb1 = &lb[(wn + 16 + fr) * 136 + quad * 8];
#pragma unroll
        for (int kk = 0; kk < 4; ++kk) {
            half8_t a0 = *reinterpret_cast<const half8_t*>(pa0 + kk * 32);
            half8_t a1 = *reinterpret_cast<const half8_t*>(pa1 + kk * 32);
            half8_t b0 = *reinterpret_cast<const half8_t*>(pb0 + kk * 32);
            half8_t b1 = *reinterpret_cast<const half8_t*>(pb1 + kk * 32);
            acc[0][0] = __builtin_amdgcn_mfma_f32_16x16x32_f16(a0, b0, acc[0][0], 0, 0, 0);
            acc[0][1] = __builtin_amdgcn_mfma_f32_16x16x32_f16(a0, b1, acc[0][1], 0, 0, 0);
            acc[1][0] = __builtin_amdgcn_mfma_f32_16x16x32_f16(a1, b0, acc[1][0], 0, 0, 0);
            acc[1][1] = __builtin_amdgcn_mfma_f32_16x16x32_f16(a1, b1, acc[1][1], 0, 0, 0);
        }
        __syncthreads();
    }

    const float bv0 = bias[nblk * 64 + wn + fr];
    const float bv1 = bias[nblk * 64 + wn + 16 + fr];
#pragma unroll
    for (int i = 0; i < 2; ++i) {
        const int ml = wm + i * 16 + quad * 4;
#pragma unroll
        for (int r = 0; r < 4; ++r) {
            Z[(size_t)(ml + r) * 1024 + nblk * 64 + wn + fr]      = acc[i][0][r] + bv0;
            Z[(size_t)(ml + r) * 1024 + nblk * 64 + wn + 16 + fr] = acc[i][1][r] + bv1;
        }
    }
}

// ---------------------------------------------------------------------------
// Persistent recurrence, cache-maintenance-free sync.
// 256 WGs x 256 thr. Group m = bid&15 owns batch rows [m*16, m*16+16);
// WG (m,n) owns hidden cols [n*64, n*64+64). Wave w holds Wh fragments for
// its 16-col strip, full K=1024, in 128 VGPRs for all steps (no split-K).
// Cross-WG h exchange via IF$ (chip-coherent): fp16 h stores are
// system-relaxed (write-through, sc0|sc1), slab loads via global_load_lds
// aux=17 (bypass L1/L2), flags system-relaxed. NO fences -> no buffer_wbl2 /
// buffer_inv anywhere in the loop.
// ---------------------------------------------------------------------------
__global__ __launch_bounds__(256, 1) void rnn_persist(
        const _Float16* __restrict__ Wh,
        _Float16* __restrict__ Hh,
        int* __restrict__ flags,
        float* __restrict__ out) {
    __shared__ __align__(16) _Float16 hL[16 * LDH];
    __shared__ __align__(16) float redL[16 * REDW];

    const int tid  = threadIdx.x;
    const int m    = blockIdx.x & 15;
    const int n    = blockIdx.x >> 4;
    const int wave = tid >> 6;
    const int lane = tid & 63;
    const int fr   = lane & 15;
    const int quad = lane >> 4;

    // Wh fragments: wave's 16 cols x K=1024 -> 32 x half8 = 128 VGPRs.
    half8_t bfrag[32];
    {
        const _Float16* wp = Wh + (size_t)(n * 64 + wave * 16 + fr) * DH + quad * 8;
#pragma unroll
        for (int ks = 0; ks < 32; ++ks)
            bfrag[ks] = *reinterpret_cast<const half8_t*>(wp + ks * 32);
    }

    const int r  = tid >> 4;          // 0..15 batch row within tile
    const int c4 = (tid & 15) * 4;    // 0..60 col within tile
    const size_t orowg = (size_t)(m * 16 + r);
    int* myflag = flags + (m * 16 + n) * 16;

    // ---- t = 0: h1 = tanh(Z1) since h0 == 0 -> out[1] + Hh buffer 1 ----
    {
        float* o1 = out + ((size_t)BATCH + orowg) * DH + n * 64 + c4;
        float4 z = *reinterpret_cast<const float4*>(o1);
        float4 v = make_float4(ftanh(z.x), ftanh(z.y), ftanh(z.z), ftanh(z.w));
        *reinterpret_cast<float4*>(o1) = v;
        H4U cv;
        cv.h[0] = (_Float16)v.x; cv.h[1] = (_Float16)v.y;
        cv.h[2] = (_Float16)v.z; cv.h[3] = (_Float16)v.w;
        __hip_atomic_store(
            (unsigned long long*)(Hh + ((size_t)BATCH + orowg) * DH + n * 64 + c4),
            cv.u, __ATOMIC_RELAXED, __HIP_MEMORY_SCOPE_SYSTEM);
        __syncthreads();   // all write-through stores vmcnt-drained
        if (tid == 0)
            __hip_atomic_store(myflag, 1, __ATOMIC_RELAXED, __HIP_MEMORY_SCOPE_SYSTEM);
    }

    for (int s = 1; s < T_STEPS; ++s) {
        // Z prefetch (own tile of out[s+1]; written only by zgemm).
        float* o = out + ((size_t)(s + 1) * BATCH + orowg) * DH + n * 64 + c4;
        float4 z = *reinterpret_cast<const float4*>(o);

        // Wait for the 16 producers of group m to finish step s.
        if (tid < 16) {
            const int* f = flags + (m * 16 + tid) * 16;
            int guard = 0;
            while (__hip_atomic_load(f, __ATOMIC_RELAXED, __HIP_MEMORY_SCOPE_SYSTEM) < s) {
                if (++guard > (1 << 24)) break;   // bailout -> visible wrongness, not hang
            }
        }
        __syncthreads();

        // Stage h_s slab (16 x 1024 fp16 = 32 KB) into LDS, bypassing L1/L2.
        const _Float16* hsrc = Hh + ((size_t)(s & 1) * BATCH + (size_t)m * 16) * DH;
#pragma unroll
        for (int i = 0; i < 8; ++i) {
            const int c   = wave * 8 + i;    // 0..31 chunks of 1 KB
            const int row = c >> 1;
            const int hf  = c & 1;
            const _Float16* src = hsrc + (size_t)row * DH + hf * 512 + lane * 8;
            __builtin_amdgcn_global_load_lds(
                (const __attribute__((address_space(1))) void*)src,
                (__attribute__((address_space(3))) void*)&hL[row * LDH + hf * 512],
                16, 0, CPOL_SYS);
        }
        __syncthreads();

        // 32 MFMAs, two interleaved accumulator chains.
        f32x4_t acc0 = {0.f, 0.f, 0.f, 0.f}, acc1 = {0.f, 0.f, 0.f, 0.f};
        const _Float16* pa = &hL[fr * LDH + quad * 8];
#pragma unroll
        for (int ks = 0; ks < 16; ++ks) {
            half8_t ae = *reinterpret_cast<const half8_t*>(pa + (2 * ks) * 32);
            half8_t ao = *reinterpret_cast<const half8_t*>(pa + (2 * ks + 1) * 32);
            acc0 = __builtin_amdgcn_mfma_f32_16x16x32_f16(ae, bfrag[2 * ks],     acc0, 0, 0, 0);
            acc1 = __builtin_amdgcn_mfma_f32_16x16x32_f16(ao, bfrag[2 * ks + 1], acc1, 0, 0, 0);
        }
        f32x4_t sum = acc0 + acc1;

        // Transpose D-layout (row=quad*4+q batch, col=wave*16+fr) via LDS.
#pragma unroll
        for (int q = 0; q < 4; ++q)
            redL[(quad * 4 + q) * REDW + wave * 16 + fr] = sum[q];
        __syncthreads();

        f32x4_t t4 = *reinterpret_cast<const f32x4_t*>(&redL[r * REDW + c4]);
        float4 v = make_float4(ftanh(t4[0] + z.x), ftanh(t4[1] + z.y),
                               ftanh(t4[2] + z.z), ftanh(t4[3] + z.w));
        *reinterpret_cast<float4*>(o) = v;
        H4U cv;
        cv.h[0] = (_Float16)v.x; cv.h[1] = (_Float16)v.y;
        cv.h[2] = (_Float16)v.z; cv.h[3] = (_Float16)v.w;
        __hip_atomic_store(
            (unsigned long long*)(Hh + ((size_t)((s + 1) & 1) * BATCH + orowg) * DH
                                  + n * 64 + c4),
            cv.u, __ATOMIC_RELAXED, __HIP_MEMORY_SCOPE_SYSTEM);

        __syncthreads();   // every thread's write-through stores drained
        if (tid == 0)
            __hip_atomic_store(myflag, s + 1, __ATOMIC_RELAXED, __HIP_MEMORY_SCOPE_SYSTEM);
    }
}

// ---------------------------------------------------------------------------
// Workspace layout (bytes):
//   [0, 2M)   Wh fp16 (1024 x 1024)
//   [2M, 4M)  Wx fp16 (1024 x 1024)
//   [4M, 5M)  Hh fp16 double buffer (2 x 256 x 1024)
//   [5M, +16K) flags int[256][16]
// ---------------------------------------------------------------------------
extern "C" void kernel_launch(void* const* d_in, const int* in_sizes, int n_in,
                              void* d_out, int out_size, void* d_ws, size_t ws_size,
                              hipStream_t stream) {
    const float* seq  = (const float*)d_in[0];   // (256, 256, 1024) fp32
    const float* W    = (const float*)d_in[1];   // (1024, 2048) fp32
    const float* bias = (const float*)d_in[2];   // (1024,) fp32
    float* out        = (float*)d_out;           // (257, 256, 1024) fp32
    _Float16* Wh      = (_Float16*)d_ws;
    _Float16* Wx      = (_Float16*)d_ws + 1024 * 1024;
    _Float16* Hh      = (_Float16*)d_ws + 2 * 1024 * 1024;
    int* flags        = (int*)((char*)d_ws + 5 * 1024 * 1024);

    hipLaunchKernelGGL(cvt_w, dim3(1024), dim3(256), 0, stream, W, Wh, Wx);
    hipLaunchKernelGGL(zero_h0, dim3(256), dim3(256), 0, stream, out, flags);
    hipLaunchKernelGGL(zgemm, dim3(16, 1024), dim3(256), 0, stream, seq, Wx, bias, out);
    hipLaunchKernelGGL(rnn_persist, dim3(256), dim3(256), 0, stream, Wh, Hh, flags, out);
}

// Round 6
// 2004.131 us; speedup vs baseline: 8.2248x; 1.0189x over previous
//
#include <hip/hip_runtime.h>

#define T_STEPS 256
#define BATCH   256
#define DIN     1024
#define DH      1024

typedef _Float16 half8_t __attribute__((ext_vector_type(8)));
typedef _Float16 half4_t __attribute__((ext_vector_type(4)));
typedef float    f32x4_t __attribute__((ext_vector_type(4)));

#define LDH  1032   // padded LDS row stride (halves) for h slab (rnn)
#define REDW 68     // padded row stride (floats) for epilogue transpose (rnn)

// aux/cpol bits on gfx950: bit0 = sc0, bit4 = sc1 -> 17 = system-scope bypass
#define CPOL_SYS 17

union H4U { half4_t h; unsigned long long u; };

// Fast tanh: 1 - 2/(exp2(2*log2e*x)+1); error ~1e-7 << fp16 h quantization.
__device__ __forceinline__ float ftanh(float x) {
    float t = x * 2.885390081777927f;   // 2*log2(e)
    float e = exp2f(t);
    float r = __builtin_amdgcn_rcpf(e + 1.0f);
    return 1.0f - 2.0f * r;
}

// ---------------------------------------------------------------------------
// Split W (1024 x 2048 fp32) into Wh = W[:, :1024] and Wx = W[:, 1024:], fp16.
// ---------------------------------------------------------------------------
__global__ __launch_bounds__(256) void cvt_w(const float* __restrict__ W,
                                             _Float16* __restrict__ Wh,
                                             _Float16* __restrict__ Wx) {
    const int part = blockIdx.x >> 9;                         // 0: Wh, 1: Wx
    size_t base = ((size_t)(blockIdx.x & 511) * 256 + threadIdx.x) * 8;
    const int n = (int)(base >> 10);
    const int k = (int)(base & 1023);
    const float4* s = reinterpret_cast<const float4*>(W + (size_t)n * 2048 + part * 1024 + k);
    float4 a = s[0], b = s[1];
    half8_t h;
    h[0] = (_Float16)a.x; h[1] = (_Float16)a.y;
    h[2] = (_Float16)a.z; h[3] = (_Float16)a.w;
    h[4] = (_Float16)b.x; h[5] = (_Float16)b.y;
    h[6] = (_Float16)b.z; h[7] = (_Float16)b.w;
    _Float16* dst = part ? Wx : Wh;
    *reinterpret_cast<half8_t*>(dst + base) = h;
}

// ---------------------------------------------------------------------------
// out[0] = zeros; block 0 zeroes the 256 sync flags with system-scope stores.
// ---------------------------------------------------------------------------
__global__ __launch_bounds__(256) void zero_h0(float* __restrict__ out,
                                               int* __restrict__ flags) {
    size_t i = (size_t)blockIdx.x * 256 + threadIdx.x;
    reinterpret_cast<float4*>(out)[i] = make_float4(0.f, 0.f, 0.f, 0.f);
    if (blockIdx.x == 0) {
#pragma unroll
        for (int j = 0; j < 16; ++j)
            __hip_atomic_store(&flags[(int)threadIdx.x * 16 + j], 0,
                               __ATOMIC_RELAXED, __HIP_MEMORY_SCOPE_SYSTEM);
    }
}

// ---------------------------------------------------------------------------
// Z = seq @ Wx^T + bias, written into out[1..256].
// M = 65536, N = 1024, K = 1024. Tile 64x64, BK=128, 256 thr = 4 waves (2x2),
// each wave 32x32 = 2x2 accs of 16x16x32 f16 MFMA.  (R4-proven body.)
// Grid: flat 16384, XCD-locality remap: nblk = (id>>3)&15,
// mblk = (id&7) + 8*(id>>7).  All 16 nblk-WGs of an m-stripe have
// id % 8 == mblk & 7 -> land on ONE XCD (round-robin dispatch), so the
// 256 KB A-stripe is fetched into exactly one L2 instead of all eight.
// Bijective: id = (mblk>>3)*128 + nblk*8 + (mblk&7).
// ---------------------------------------------------------------------------
__global__ __launch_bounds__(256) void zgemm(const float* __restrict__ seq,
                                             const _Float16* __restrict__ Wx,
                                             const float* __restrict__ bias,
                                             float* __restrict__ out) {
    __shared__ _Float16 la[64 * 136];
    __shared__ _Float16 lb[64 * 136];

    const int tid  = threadIdx.x;
    const int id   = blockIdx.x;            // 0..16383
    const int nblk = (id >> 3) & 15;        // 0..15
    const int mblk = (id & 7) + 8 * (id >> 7);  // 0..1023

    const float* __restrict__ X = seq + (size_t)mblk * 64 * 1024;
    float* __restrict__ Z = out + (size_t)BATCH * DH + (size_t)mblk * 64 * 1024;

    const int ar = tid >> 2;
    const int ac = (tid & 3) * 32;
    const int br = tid >> 2;
    const int bc = (tid & 3) * 32;
    const _Float16* Bsrc = Wx + (size_t)(nblk * 64 + br) * 1024;

    float4 af[8];
    uint4  bp[4];

    auto load_tiles = [&](int kb) {
        const float4* s4 = reinterpret_cast<const float4*>(X + (size_t)ar * 1024 + kb + ac);
#pragma unroll
        for (int i = 0; i < 8; ++i) af[i] = s4[i];
        const uint4* sb = reinterpret_cast<const uint4*>(Bsrc + kb + bc);
#pragma unroll
        for (int i = 0; i < 4; ++i) bp[i] = sb[i];
    };
    auto store_tiles = [&]() {
#pragma unroll
        for (int i = 0; i < 4; ++i) {
            half8_t h;
            h[0] = (_Float16)af[2 * i].x; h[1] = (_Float16)af[2 * i].y;
            h[2] = (_Float16)af[2 * i].z; h[3] = (_Float16)af[2 * i].w;
            h[4] = (_Float16)af[2 * i + 1].x; h[5] = (_Float16)af[2 * i + 1].y;
            h[6] = (_Float16)af[2 * i + 1].z; h[7] = (_Float16)af[2 * i + 1].w;
            *reinterpret_cast<half8_t*>(&la[ar * 136 + ac + 8 * i]) = h;
        }
        uint4* d = reinterpret_cast<uint4*>(&lb[br * 136 + bc]);
#pragma unroll
        for (int i = 0; i < 4; ++i) d[i] = bp[i];
    };

    const int wave = tid >> 6;
    const int lane = tid & 63;
    const int fr   = lane & 15;
    const int quad = lane >> 4;
    const int wm   = (wave >> 1) * 32;
    const int wn   = (wave & 1) * 32;

    f32x4_t acc[2][2] = {{{0.f,0.f,0.f,0.f},{0.f,0.f,0.f,0.f}},
                         {{0.f,0.f,0.f,0.f},{0.f,0.f,0.f,0.f}}};

    load_tiles(0);
#pragma unroll 1
    for (int it = 0; it < 8; ++it) {
        store_tiles();
        __syncthreads();
        if (it < 7) load_tiles((it + 1) * 128);
        const _Float16* pa0 = &la[(wm + fr) * 136 + quad * 8];
        const _Float16* pa1 = &la[(wm + 16 + fr) * 136 + quad * 8];
        const _Float16* pb0 = &lb[(wn + fr) * 136 + quad * 8];
        const _Float16* pb1 = &lb[(wn + 16 + fr) * 136 + quad * 8];
#pragma unroll
        for (int kk = 0; kk < 4; ++kk) {
            half8_t a0 = *reinterpret_cast<const half8_t*>(pa0 + kk * 32);
            half8_t a1 = *reinterpret_cast<const half8_t*>(pa1 + kk * 32);
            half8_t b0 = *reinterpret_cast<const half8_t*>(pb0 + kk * 32);
            half8_t b1 = *reinterpret_cast<const half8_t*>(pb1 + kk * 32);
            acc[0][0] = __builtin_amdgcn_mfma_f32_16x16x32_f16(a0, b0, acc[0][0], 0, 0, 0);
            acc[0][1] = __builtin_amdgcn_mfma_f32_16x16x32_f16(a0, b1, acc[0][1], 0, 0, 0);
            acc[1][0] = __builtin_amdgcn_mfma_f32_16x16x32_f16(a1, b0, acc[1][0], 0, 0, 0);
            acc[1][1] = __builtin_amdgcn_mfma_f32_16x16x32_f16(a1, b1, acc[1][1], 0, 0, 0);
        }
        __syncthreads();
    }

    const float bv0 = bias[nblk * 64 + wn + fr];
    const float bv1 = bias[nblk * 64 + wn + 16 + fr];
#pragma unroll
    for (int i = 0; i < 2; ++i) {
        const int ml = wm + i * 16 + quad * 4;
#pragma unroll
        for (int r = 0; r < 4; ++r) {
            Z[(size_t)(ml + r) * 1024 + nblk * 64 + wn + fr]      = acc[i][0][r] + bv0;
            Z[(size_t)(ml + r) * 1024 + nblk * 64 + wn + 16 + fr] = acc[i][1][r] + bv1;
        }
    }
}

// ---------------------------------------------------------------------------
// Persistent recurrence, cache-maintenance-free sync (byte-identical to R4).
// ---------------------------------------------------------------------------
__global__ __launch_bounds__(256, 1) void rnn_persist(
        const _Float16* __restrict__ Wh,
        _Float16* __restrict__ Hh,
        int* __restrict__ flags,
        float* __restrict__ out) {
    __shared__ __align__(16) _Float16 hL[16 * LDH];
    __shared__ __align__(16) float redL[16 * REDW];

    const int tid  = threadIdx.x;
    const int m    = blockIdx.x & 15;
    const int n    = blockIdx.x >> 4;
    const int wave = tid >> 6;
    const int lane = tid & 63;
    const int fr   = lane & 15;
    const int quad = lane >> 4;

    // Wh fragments: wave's 16 cols x K=1024 -> 32 x half8 = 128 VGPRs.
    half8_t bfrag[32];
    {
        const _Float16* wp = Wh + (size_t)(n * 64 + wave * 16 + fr) * DH + quad * 8;
#pragma unroll
        for (int ks = 0; ks < 32; ++ks)
            bfrag[ks] = *reinterpret_cast<const half8_t*>(wp + ks * 32);
    }

    const int r  = tid >> 4;          // 0..15 batch row within tile
    const int c4 = (tid & 15) * 4;    // 0..60 col within tile
    const size_t orowg = (size_t)(m * 16 + r);
    int* myflag = flags + (m * 16 + n) * 16;

    // ---- t = 0: h1 = tanh(Z1) since h0 == 0 -> out[1] + Hh buffer 1 ----
    {
        float* o1 = out + ((size_t)BATCH + orowg) * DH + n * 64 + c4;
        float4 z = *reinterpret_cast<const float4*>(o1);
        float4 v = make_float4(ftanh(z.x), ftanh(z.y), ftanh(z.z), ftanh(z.w));
        *reinterpret_cast<float4*>(o1) = v;
        H4U cv;
        cv.h[0] = (_Float16)v.x; cv.h[1] = (_Float16)v.y;
        cv.h[2] = (_Float16)v.z; cv.h[3] = (_Float16)v.w;
        __hip_atomic_store(
            (unsigned long long*)(Hh + ((size_t)BATCH + orowg) * DH + n * 64 + c4),
            cv.u, __ATOMIC_RELAXED, __HIP_MEMORY_SCOPE_SYSTEM);
        __syncthreads();   // all write-through stores vmcnt-drained
        if (tid == 0)
            __hip_atomic_store(myflag, 1, __ATOMIC_RELAXED, __HIP_MEMORY_SCOPE_SYSTEM);
    }

    for (int s = 1; s < T_STEPS; ++s) {
        // Z prefetch (own tile of out[s+1]; written only by zgemm).
        float* o = out + ((size_t)(s + 1) * BATCH + orowg) * DH + n * 64 + c4;
        float4 z = *reinterpret_cast<const float4*>(o);

        // Wait for the 16 producers of group m to finish step s.
        if (tid < 16) {
            const int* f = flags + (m * 16 + tid) * 16;
            int guard = 0;
            while (__hip_atomic_load(f, __ATOMIC_RELAXED, __HIP_MEMORY_SCOPE_SYSTEM) < s) {
                if (++guard > (1 << 24)) break;   // bailout -> visible wrongness, not hang
            }
        }
        __syncthreads();

        // Stage h_s slab (16 x 1024 fp16 = 32 KB) into LDS, bypassing L1/L2.
        const _Float16* hsrc = Hh + ((size_t)(s & 1) * BATCH + (size_t)m * 16) * DH;
#pragma unroll
        for (int i = 0; i < 8; ++i) {
            const int c   = wave * 8 + i;    // 0..31 chunks of 1 KB
            const int row = c >> 1;
            const int hf  = c & 1;
            const _Float16* src = hsrc + (size_t)row * DH + hf * 512 + lane * 8;
            __builtin_amdgcn_global_load_lds(
                (const __attribute__((address_space(1))) void*)src,
                (__attribute__((address_space(3))) void*)&hL[row * LDH + hf * 512],
                16, 0, CPOL_SYS);
        }
        __syncthreads();

        // 32 MFMAs, two interleaved accumulator chains.
        f32x4_t acc0 = {0.f, 0.f, 0.f, 0.f}, acc1 = {0.f, 0.f, 0.f, 0.f};
        const _Float16* pa = &hL[fr * LDH + quad * 8];
#pragma unroll
        for (int ks = 0; ks < 16; ++ks) {
            half8_t ae = *reinterpret_cast<const half8_t*>(pa + (2 * ks) * 32);
            half8_t ao = *reinterpret_cast<const half8_t*>(pa + (2 * ks + 1) * 32);
            acc0 = __builtin_amdgcn_mfma_f32_16x16x32_f16(ae, bfrag[2 * ks],     acc0, 0, 0, 0);
            acc1 = __builtin_amdgcn_mfma_f32_16x16x32_f16(ao, bfrag[2 * ks + 1], acc1, 0, 0, 0);
        }
        f32x4_t sum = acc0 + acc1;

        // Transpose D-layout (row=quad*4+q batch, col=wave*16+fr) via LDS.
#pragma unroll
        for (int q = 0; q < 4; ++q)
            redL[(quad * 4 + q) * REDW + wave * 16 + fr] = sum[q];
        __syncthreads();

        f32x4_t t4 = *reinterpret_cast<const f32x4_t*>(&redL[r * REDW + c4]);
        float4 v = make_float4(ftanh(t4[0] + z.x), ftanh(t4[1] + z.y),
                               ftanh(t4[2] + z.z), ftanh(t4[3] + z.w));
        *reinterpret_cast<float4*>(o) = v;
        H4U cv;
        cv.h[0] = (_Float16)v.x; cv.h[1] = (_Float16)v.y;
        cv.h[2] = (_Float16)v.z; cv.h[3] = (_Float16)v.w;
        __hip_atomic_store(
            (unsigned long long*)(Hh + ((size_t)((s + 1) & 1) * BATCH + orowg) * DH
                                  + n * 64 + c4),
            cv.u, __ATOMIC_RELAXED, __HIP_MEMORY_SCOPE_SYSTEM);

        __syncthreads();   // every thread's write-through stores drained
        if (tid == 0)
            __hip_atomic_store(myflag, s + 1, __ATOMIC_RELAXED, __HIP_MEMORY_SCOPE_SYSTEM);
    }
}

// ---------------------------------------------------------------------------
// Workspace layout (bytes):
//   [0, 2M)   Wh fp16 (1024 x 1024)
//   [2M, 4M)  Wx fp16 (1024 x 1024)
//   [4M, 5M)  Hh fp16 double buffer (2 x 256 x 1024)
//   [5M, +16K) flags int[256][16]
// ---------------------------------------------------------------------------
extern "C" void kernel_launch(void* const* d_in, const int* in_sizes, int n_in,
                              void* d_out, int out_size, void* d_ws, size_t ws_size,
                              hipStream_t stream) {
    const float* seq  = (const float*)d_in[0];   // (256, 256, 1024) fp32
    const float* W    = (const float*)d_in[1];   // (1024, 2048) fp32
    const float* bias = (const float*)d_in[2];   // (1024,) fp32
    float* out        = (float*)d_out;           // (257, 256, 1024) fp32
    _Float16* Wh      = (_Float16*)d_ws;
    _Float16* Wx      = (_Float16*)d_ws + 1024 * 1024;
    _Float16* Hh      = (_Float16*)d_ws + 2 * 1024 * 1024;
    int* flags        = (int*)((char*)d_ws + 5 * 1024 * 1024);

    hipLaunchKernelGGL(cvt_w, dim3(1024), dim3(256), 0, stream, W, Wh, Wx);
    hipLaunchKernelGGL(zero_h0, dim3(256), dim3(256), 0, stream, out, flags);
    hipLaunchKernelGGL(zgemm, dim3(16384), dim3(256), 0, stream, seq, Wx, bias, out);
    hipLaunchKernelGGL(rnn_persist, dim3(256), dim3(256), 0, stream, Wh, Hh, flags, out);
}

// Round 7
// 1351.089 us; speedup vs baseline: 12.2002x; 1.4833x over previous
//
#include <hip/hip_runtime.h>

#define T_STEPS 256
#define BATCH   256
#define DIN     1024
#define DH      1024

typedef _Float16 half8_t __attribute__((ext_vector_type(8)));
typedef _Float16 half4_t __attribute__((ext_vector_type(4)));
typedef float    f32x4_t __attribute__((ext_vector_type(4)));

#define LDH  1032   // padded LDS row stride (halves) for h/x slabs
#define REDW 68     // padded row stride (floats) for epilogue transpose

// aux/cpol bits on gfx950: bit0 = sc0, bit4 = sc1 -> 17 = system-scope bypass
#define CPOL_SYS 17

union H4U { half4_t h; unsigned long long u; };

// Fast tanh: 1 - 2/(exp2(2*log2e*x)+1); error ~1e-7 << fp16 h quantization.
__device__ __forceinline__ float ftanh(float x) {
    float t = x * 2.885390081777927f;   // 2*log2(e)
    float e = exp2f(t);
    float r = __builtin_amdgcn_rcpf(e + 1.0f);
    return 1.0f - 2.0f * r;
}

// ---------------------------------------------------------------------------
// Split W (1024 x 2048 fp32) into Wh = W[:, :1024] and Wx = W[:, 1024:], fp16.
// ---------------------------------------------------------------------------
__global__ __launch_bounds__(256) void cvt_w(const float* __restrict__ W,
                                             _Float16* __restrict__ Wh,
                                             _Float16* __restrict__ Wx) {
    const int part = blockIdx.x >> 9;                         // 0: Wh, 1: Wx
    size_t base = ((size_t)(blockIdx.x & 511) * 256 + threadIdx.x) * 8;
    const int n = (int)(base >> 10);
    const int k = (int)(base & 1023);
    const float4* s = reinterpret_cast<const float4*>(W + (size_t)n * 2048 + part * 1024 + k);
    float4 a = s[0], b = s[1];
    half8_t h;
    h[0] = (_Float16)a.x; h[1] = (_Float16)a.y;
    h[2] = (_Float16)a.z; h[3] = (_Float16)a.w;
    h[4] = (_Float16)b.x; h[5] = (_Float16)b.y;
    h[6] = (_Float16)b.z; h[7] = (_Float16)b.w;
    _Float16* dst = part ? Wx : Wh;
    *reinterpret_cast<half8_t*>(dst + base) = h;
}

// ---------------------------------------------------------------------------
// out[0] = zeros; block 0 zeroes the 256 sync flags with system-scope stores.
// ---------------------------------------------------------------------------
__global__ __launch_bounds__(256) void zero_h0(float* __restrict__ out,
                                               int* __restrict__ flags) {
    size_t i = (size_t)blockIdx.x * 256 + threadIdx.x;
    reinterpret_cast<float4*>(out)[i] = make_float4(0.f, 0.f, 0.f, 0.f);
    if (blockIdx.x == 0) {
#pragma unroll
        for (int j = 0; j < 16; ++j)
            __hip_atomic_store(&flags[(int)threadIdx.x * 16 + j], 0,
                               __ATOMIC_RELAXED, __HIP_MEMORY_SCOPE_SYSTEM);
    }
}

// ---------------------------------------------------------------------------
// FUSED persistent recurrence: h_{s+1} = tanh(Wh h_s + Wx x_s + b).
// 256 WGs x 256 thr, 1/CU. Group m = bid&15 owns batch rows [m*16,m*16+16);
// WG (m,n) owns hidden cols [n*64,n*64+64). Wave w holds BOTH Wh and Wx
// fragments for its 16 cols (K=2048 -> 64 x half8 = 256 VGPRs, resident all
// steps). Per step: issue x-slab loads (seq, no dependency -> hidden under
// flag poll) -> poll peers -> gload_lds h-slab (IF$-coherent bypass) +
// cvt x -> LDS -> 64 MFMAs -> LDS transpose -> +bias, tanh -> store out +
// Hh (write-through) -> flag. Flag/Hh protocol byte-identical to the
// R4-proven version; the WG consumes exactly the Z it used to read, so
// fusing adds ZERO new synchronization. zgemm is eliminated entirely.
// ---------------------------------------------------------------------------
__global__ __launch_bounds__(256, 1) void rnn_fused(
        const _Float16* __restrict__ Wh,
        const _Float16* __restrict__ Wx,
        const float* __restrict__ bias,
        const float* __restrict__ seq,
        _Float16* __restrict__ Hh,
        int* __restrict__ flags,
        float* __restrict__ out) {
    __shared__ __align__(16) _Float16 hL[16 * LDH];
    __shared__ __align__(16) _Float16 xL[16 * LDH];
    __shared__ __align__(16) float redL[16 * REDW];

    const int tid  = threadIdx.x;
    const int m    = blockIdx.x & 15;
    const int n    = blockIdx.x >> 4;
    const int wave = tid >> 6;
    const int lane = tid & 63;
    const int fr   = lane & 15;
    const int quad = lane >> 4;

    // Weight fragments: wave's 16 output cols, K = 2048 ([Wh | Wx]).
    half8_t wfrag[64];
    {
        const _Float16* wph = Wh + (size_t)(n * 64 + wave * 16 + fr) * DH + quad * 8;
        const _Float16* wpx = Wx + (size_t)(n * 64 + wave * 16 + fr) * DH + quad * 8;
#pragma unroll
        for (int ks = 0; ks < 32; ++ks) {
            wfrag[ks]      = *reinterpret_cast<const half8_t*>(wph + ks * 32);
            wfrag[32 + ks] = *reinterpret_cast<const half8_t*>(wpx + ks * 32);
        }
    }

    const int r  = tid >> 4;          // 0..15 batch row within tile
    const int c4 = (tid & 15) * 4;    // 0..60 col within tile
    const size_t orowg = (size_t)(m * 16 + r);
    int* myflag = flags + (m * 16 + n) * 16;

    // x staging map: row xr = tid>>4, float-offset (tid&15)*4 + c*64.
    // Per instruction: 4 rows x 256 B dense -> fully coalesced.
    const int xr = tid >> 4;
    const int xc = (tid & 15) * 4;
    const float* xbase = seq + ((size_t)m * 16 + xr) * DH + xc;

    const float4 bv4 = *reinterpret_cast<const float4*>(bias + n * 64 + c4);

    // ---- s = 0: h1 = tanh(Wx x_0 + b) since h0 == 0 ----
    {
        float4 xv[16];
        const float* p = xbase;   // seq[0]
#pragma unroll
        for (int c = 0; c < 16; ++c)
            xv[c] = *reinterpret_cast<const float4*>(p + c * 64);
#pragma unroll
        for (int c = 0; c < 16; ++c) {
            half4_t h4;
            h4[0] = (_Float16)xv[c].x; h4[1] = (_Float16)xv[c].y;
            h4[2] = (_Float16)xv[c].z; h4[3] = (_Float16)xv[c].w;
            *reinterpret_cast<half4_t*>(&xL[xr * LDH + xc + c * 64]) = h4;
        }
        __syncthreads();

        f32x4_t acc0 = {0.f,0.f,0.f,0.f}, acc1 = {0.f,0.f,0.f,0.f};
        const _Float16* pax = &xL[fr * LDH + quad * 8];
#pragma unroll
        for (int ks = 0; ks < 16; ++ks) {
            half8_t a0 = *reinterpret_cast<const half8_t*>(pax + (2 * ks) * 32);
            half8_t a1 = *reinterpret_cast<const half8_t*>(pax + (2 * ks + 1) * 32);
            acc0 = __builtin_amdgcn_mfma_f32_16x16x32_f16(a0, wfrag[32 + 2 * ks],     acc0, 0, 0, 0);
            acc1 = __builtin_amdgcn_mfma_f32_16x16x32_f16(a1, wfrag[32 + 2 * ks + 1], acc1, 0, 0, 0);
        }
        f32x4_t sum = acc0 + acc1;
#pragma unroll
        for (int q = 0; q < 4; ++q)
            redL[(quad * 4 + q) * REDW + wave * 16 + fr] = sum[q];
        __syncthreads();

        f32x4_t t4 = *reinterpret_cast<const f32x4_t*>(&redL[r * REDW + c4]);
        float4 v = make_float4(ftanh(t4[0] + bv4.x), ftanh(t4[1] + bv4.y),
                               ftanh(t4[2] + bv4.z), ftanh(t4[3] + bv4.w));
        *reinterpret_cast<float4*>(
            out + ((size_t)BATCH + orowg) * DH + n * 64 + c4) = v;
        H4U cv;
        cv.h[0] = (_Float16)v.x; cv.h[1] = (_Float16)v.y;
        cv.h[2] = (_Float16)v.z; cv.h[3] = (_Float16)v.w;
        __hip_atomic_store(
            (unsigned long long*)(Hh + ((size_t)BATCH + orowg) * DH + n * 64 + c4),
            cv.u, __ATOMIC_RELAXED, __HIP_MEMORY_SCOPE_SYSTEM);
        __syncthreads();   // write-through stores vmcnt-drained
        if (tid == 0)
            __hip_atomic_store(myflag, 1, __ATOMIC_RELAXED, __HIP_MEMORY_SCOPE_SYSTEM);
    }

    for (int s = 1; s < T_STEPS; ++s) {
        // x_s loads: no cross-WG dependency -> issue BEFORE the poll so
        // HBM/L2 latency hides under the flag wait.
        float4 xv[16];
        const float* p = xbase + (size_t)s * (BATCH * DH);
#pragma unroll
        for (int c = 0; c < 16; ++c)
            xv[c] = *reinterpret_cast<const float4*>(p + c * 64);

        // Wait for the 16 producers of group m to finish step s.
        if (tid < 16) {
            const int* f = flags + (m * 16 + tid) * 16;
            int guard = 0;
            while (__hip_atomic_load(f, __ATOMIC_RELAXED, __HIP_MEMORY_SCOPE_SYSTEM) < s) {
                if (++guard > (1 << 24)) break;   // bailout -> visible wrongness, not hang
            }
        }
        __syncthreads();

        // Stage h_s slab (16 x 1024 fp16 = 32 KB) into LDS, bypassing L1/L2.
        const _Float16* hsrc = Hh + ((size_t)(s & 1) * BATCH + (size_t)m * 16) * DH;
#pragma unroll
        for (int i = 0; i < 8; ++i) {
            const int c   = wave * 8 + i;    // 0..31 chunks of 1 KB
            const int row = c >> 1;
            const int hf  = c & 1;
            const _Float16* src = hsrc + (size_t)row * DH + hf * 512 + lane * 8;
            __builtin_amdgcn_global_load_lds(
                (const __attribute__((address_space(1))) void*)src,
                (__attribute__((address_space(3))) void*)&hL[row * LDH + hf * 512],
                16, 0, CPOL_SYS);
        }
        // Stage x_s (cvt fp32 -> fp16). Safe: all waves passed step s-1's
        // final barrier, so nobody is still reading xL.
#pragma unroll
        for (int c = 0; c < 16; ++c) {
            half4_t h4;
            h4[0] = (_Float16)xv[c].x; h4[1] = (_Float16)xv[c].y;
            h4[2] = (_Float16)xv[c].z; h4[3] = (_Float16)xv[c].w;
            *reinterpret_cast<half4_t*>(&xL[xr * LDH + xc + c * 64]) = h4;
        }
        __syncthreads();   // drains gload_lds (vmcnt) + xL writes (lgkm)

        // 64 MFMAs: K = 2048 over [h | x], two interleaved chains.
        f32x4_t acc0 = {0.f,0.f,0.f,0.f}, acc1 = {0.f,0.f,0.f,0.f};
        const _Float16* pah = &hL[fr * LDH + quad * 8];
        const _Float16* pax = &xL[fr * LDH + quad * 8];
#pragma unroll
        for (int ks = 0; ks < 16; ++ks) {
            half8_t a0 = *reinterpret_cast<const half8_t*>(pah + (2 * ks) * 32);
            half8_t a1 = *reinterpret_cast<const half8_t*>(pah + (2 * ks + 1) * 32);
            acc0 = __builtin_amdgcn_mfma_f32_16x16x32_f16(a0, wfrag[2 * ks],     acc0, 0, 0, 0);
            acc1 = __builtin_amdgcn_mfma_f32_16x16x32_f16(a1, wfrag[2 * ks + 1], acc1, 0, 0, 0);
        }
#pragma unroll
        for (int ks = 0; ks < 16; ++ks) {
            half8_t a0 = *reinterpret_cast<const half8_t*>(pax + (2 * ks) * 32);
            half8_t a1 = *reinterpret_cast<const half8_t*>(pax + (2 * ks + 1) * 32);
            acc0 = __builtin_amdgcn_mfma_f32_16x16x32_f16(a0, wfrag[32 + 2 * ks],     acc0, 0, 0, 0);
            acc1 = __builtin_amdgcn_mfma_f32_16x16x32_f16(a1, wfrag[32 + 2 * ks + 1], acc1, 0, 0, 0);
        }
        f32x4_t sum = acc0 + acc1;

        // Transpose D-layout (row=quad*4+q batch, col=wave*16+fr) via LDS.
#pragma unroll
        for (int q = 0; q < 4; ++q)
            redL[(quad * 4 + q) * REDW + wave * 16 + fr] = sum[q];
        __syncthreads();

        f32x4_t t4 = *reinterpret_cast<const f32x4_t*>(&redL[r * REDW + c4]);
        float4 v = make_float4(ftanh(t4[0] + bv4.x), ftanh(t4[1] + bv4.y),
                               ftanh(t4[2] + bv4.z), ftanh(t4[3] + bv4.w));
        *reinterpret_cast<float4*>(
            out + ((size_t)(s + 1) * BATCH + orowg) * DH + n * 64 + c4) = v;
        H4U cv;
        cv.h[0] = (_Float16)v.x; cv.h[1] = (_Float16)v.y;
        cv.h[2] = (_Float16)v.z; cv.h[3] = (_Float16)v.w;
        __hip_atomic_store(
            (unsigned long long*)(Hh + ((size_t)((s + 1) & 1) * BATCH + orowg) * DH
                                  + n * 64 + c4),
            cv.u, __ATOMIC_RELAXED, __HIP_MEMORY_SCOPE_SYSTEM);

        __syncthreads();   // every thread's write-through stores drained
        if (tid == 0)
            __hip_atomic_store(myflag, s + 1, __ATOMIC_RELAXED, __HIP_MEMORY_SCOPE_SYSTEM);
    }
}

// ---------------------------------------------------------------------------
// Workspace layout (bytes):
//   [0, 2M)   Wh fp16 (1024 x 1024)
//   [2M, 4M)  Wx fp16 (1024 x 1024)
//   [4M, 5M)  Hh fp16 double buffer (2 x 256 x 1024)
//   [5M, +16K) flags int[256][16]
// ---------------------------------------------------------------------------
extern "C" void kernel_launch(void* const* d_in, const int* in_sizes, int n_in,
                              void* d_out, int out_size, void* d_ws, size_t ws_size,
                              hipStream_t stream) {
    const float* seq  = (const float*)d_in[0];   // (256, 256, 1024) fp32
    const float* W    = (const float*)d_in[1];   // (1024, 2048) fp32
    const float* bias = (const float*)d_in[2];   // (1024,) fp32
    float* out        = (float*)d_out;           // (257, 256, 1024) fp32
    _Float16* Wh      = (_Float16*)d_ws;
    _Float16* Wx      = (_Float16*)d_ws + 1024 * 1024;
    _Float16* Hh      = (_Float16*)d_ws + 2 * 1024 * 1024;
    int* flags        = (int*)((char*)d_ws + 5 * 1024 * 1024);

    hipLaunchKernelGGL(cvt_w, dim3(1024), dim3(256), 0, stream, W, Wh, Wx);
    hipLaunchKernelGGL(zero_h0, dim3(256), dim3(256), 0, stream, out, flags);
    hipLaunchKernelGGL(rnn_fused, dim3(256), dim3(256), 0, stream,
                       Wh, Wx, bias, seq, Hh, flags, out);
}